// Round 2
// baseline (72.696 us; speedup 1.0000x reference)
//
#include <hip/hip_runtime.h>
#include <math.h>

// Problem constants (mirror the JAX reference exactly)
#define N_LOC3 9604   // 98*98
#define N_LOC4 2401   // 49*49
#define N_LOC5 625    // 25*25
#define N_A3   28812  // N_LOC3*3
#define N_A4   36015  // N_A3 + N_LOC4*3
#define N_TOTAL 37890 // N_A4 + N_LOC5*3
#define N_GT   64

// SCALE_CLAMP = log(224/8) = log(28.0), computed in double, cast to f32 at the min()
#define SCALE_CLAMP_F 3.3322045101752038f
#define SENTINEL (-100000000.0f)

__global__ __launch_bounds__(256) void rpn_fused_kernel(
    const float* __restrict__ loc3,
    const float* __restrict__ loc4,
    const float* __restrict__ loc5,
    const float* __restrict__ deltas,
    const float* __restrict__ gt,
    float* __restrict__ out)
{
    __shared__ float sgt[N_GT * 5];
    __shared__ float sarea[N_GT];

    const int tid = threadIdx.x;
    for (int i = tid; i < N_GT * 5; i += blockDim.x) sgt[i] = gt[i];
    __syncthreads();
    if (tid < N_GT) {
        // a2 = (x2-x1)*(y2-y1), fp32 as in reference _iou
        sarea[tid] = (sgt[tid*5 + 2] - sgt[tid*5 + 0]) * (sgt[tid*5 + 3] - sgt[tid*5 + 1]);
    }
    __syncthreads();

    const int a = blockIdx.x * blockDim.x + tid;
    if (a >= N_TOTAL) return;

    // ---- Anchor reconstruction (level, location, aspect ratio) ----
    int stride_i, rel;
    const float* loc;
    if (a < N_A3)      { stride_i = 8;  loc = loc3; rel = a; }
    else if (a < N_A4) { stride_i = 16; loc = loc4; rel = a - N_A3; }
    else               { stride_i = 32; loc = loc5; rel = a - N_A4; }
    const int li = rel / 3;
    const int ar = rel - li * 3;   // 0 -> 0.5, 1 -> 1.0, 2 -> 2.0

    const float2 xy = ((const float2*)loc)[li];
    const float xc = xy.x, yc = xy.y;

    // w,h computed in double (Python math.sqrt path), halved in double, cast to f32
    const double s4   = 4.0 * (double)stride_i;
    const double area = s4 * s4;
    const double ard  = (ar == 0) ? 0.5 : (ar == 1 ? 1.0 : 2.0);
    const double wd   = sqrt(area / ard);
    const double hd   = area / wd;
    const float hw = (float)(wd * 0.5);
    const float hh = (float)(hd * 0.5);

    const float x1 = xc - hw, y1 = yc - hh;
    const float x2 = xc + hw, y2 = yc + hh;

    // anchor-derived values (fp32, reference op order)
    const float wa = x2 - x1;
    const float ha = y2 - y1;
    const float xa = x1 + wa * 0.5f;
    const float ya = y1 + ha * 0.5f;

    // ---- _apply_deltas -> proposals ----
    const float4 d = ((const float4*)deltas)[a];
    const float dw = fminf(d.z, SCALE_CLAMP_F);
    const float dh = fminf(d.w, SCALE_CLAMP_F);
    const float xp = d.x * wa + xa;
    const float yp = d.y * ha + ya;
    const float wp = expf(dw) * wa;
    const float hp = expf(dh) * ha;
    float4 prop;
    prop.x = xp - wp * 0.5f;
    prop.y = yp - hp * 0.5f;
    prop.z = xp + wp * 0.5f;
    prop.w = yp + hp * 0.5f;
    ((float4*)out)[a] = prop;   // proposals: out[0 .. N_TOTAL*4)

    // ---- _match: IoU vs 64 gt, first-argmax ----
    const float a1 = wa * ha;
    float best = -1.0f;  // all IoUs >= 0, so j=0 always taken first
    int bidx = 0;
    #pragma unroll 8
    for (int j = 0; j < N_GT; ++j) {
        const float gx1 = sgt[j*5 + 0];
        const float gy1 = sgt[j*5 + 1];
        const float gx2 = sgt[j*5 + 2];
        const float gy2 = sgt[j*5 + 3];
        const float ltx = fmaxf(x1, gx1);
        const float lty = fmaxf(y1, gy1);
        const float rbx = fminf(x2, gx2);
        const float rby = fminf(y2, gy2);
        const float iw = fmaxf(rbx - ltx, 0.0f);
        const float ih = fmaxf(rby - lty, 0.0f);
        const float inter = iw * ih;
        const float uni = a1 + sarea[j] - inter;
        const float iou = inter / uni;
        if (iou > best) { best = iou; bidx = j; }  // strict > => first argmax
    }

    // sentinel ladder: q<=0.3 -> -1 ; 0.3<q<0.6 -> -1e8 ; else gt row
    float m0, m1, m2, m3, m4;
    if (best <= 0.3f) {
        m0 = m1 = m2 = m3 = m4 = -1.0f;
    } else if (best < 0.6f) {
        m0 = m1 = m2 = m3 = m4 = SENTINEL;
    } else {
        m0 = sgt[bidx*5 + 0];
        m1 = sgt[bidx*5 + 1];
        m2 = sgt[bidx*5 + 2];
        m3 = sgt[bidx*5 + 3];
        m4 = sgt[bidx*5 + 4];
    }
    // matched_gt: out[N_TOTAL*4 .. N_TOTAL*9)
    float* mout = out + N_TOTAL * 4 + a * 5;
    mout[0] = m0; mout[1] = m1; mout[2] = m2; mout[3] = m3; mout[4] = m4;

    // ---- _get_deltas ----
    float o0, o1, o2, o3;
    if (m0 < 0.0f) {
        o0 = o1 = o2 = o3 = SENTINEL;
    } else {
        const float wg = fmaxf(m2 - m0, 1.0f);
        const float hg = fmaxf(m3 - m1, 1.0f);
        const float xg = m0 + wg * 0.5f;
        const float yg = m1 + hg * 0.5f;
        o0 = (xg - xa) / wa;
        o1 = (yg - ya) / ha;
        o2 = logf(wg / wa);
        o3 = logf(hg / ha);
    }
    // gt_deltas: out[N_TOTAL*9 .. N_TOTAL*13)  (base only 8B-aligned -> scalar stores)
    float* gout = out + N_TOTAL * 9 + a * 4;
    gout[0] = o0; gout[1] = o1; gout[2] = o2; gout[3] = o3;
}

extern "C" void kernel_launch(void* const* d_in, const int* in_sizes, int n_in,
                              void* d_out, int out_size, void* d_ws, size_t ws_size,
                              hipStream_t stream) {
    const float* loc3   = (const float*)d_in[0];
    const float* loc4   = (const float*)d_in[1];
    const float* loc5   = (const float*)d_in[2];
    const float* deltas = (const float*)d_in[3];
    const float* gt     = (const float*)d_in[4];
    float* out = (float*)d_out;

    const int block = 256;
    const int grid = (N_TOTAL + block - 1) / block;  // 149 blocks
    rpn_fused_kernel<<<grid, block, 0, stream>>>(loc3, loc4, loc5, deltas, gt, out);
}

// Round 3
// 68.078 us; speedup vs baseline: 1.0678x; 1.0678x over previous
//
#include <hip/hip_runtime.h>
#include <math.h>

// Problem constants (mirror the JAX reference exactly)
#define N_A3    28812  // 98*98*3
#define N_A4    36015  // N_A3 + 49*49*3
#define N_TOTAL 37890  // N_A4 + 25*25*3
#define N_GT    64

#define SCALE_CLAMP_F 3.3322045101752038f   // (float)log(224/8)
#define SENTINEL (-100000000.0f)

// One anchor per 4-lane quad: sub-lane s scans GT j in [s*16, s*16+16),
// argmax carried as (inter, union) pair -> no division in the loop.
// Final quality = bi/bu, bitwise identical to reference's winning IoU.
__global__ __launch_bounds__(256) void rpn_fused_v2(
    const float* __restrict__ loc3,
    const float* __restrict__ loc4,
    const float* __restrict__ loc5,
    const float* __restrict__ deltas,
    const float* __restrict__ gt,
    float* __restrict__ out,
    float hw_a, float hh_a,   // ar=0.5 half-w/h at p3 (host double math)
    float hw_c, float hh_c)   // ar=2.0 half-w/h at p3
{
    __shared__ float sgt[N_GT * 5];
    __shared__ float sarea[N_GT];

    const int tid = threadIdx.x;
    if (tid < N_GT) {
        const float g0 = gt[tid * 5 + 0];
        const float g1 = gt[tid * 5 + 1];
        const float g2 = gt[tid * 5 + 2];
        const float g3 = gt[tid * 5 + 3];
        const float g4 = gt[tid * 5 + 4];
        sgt[tid * 5 + 0] = g0; sgt[tid * 5 + 1] = g1; sgt[tid * 5 + 2] = g2;
        sgt[tid * 5 + 3] = g3; sgt[tid * 5 + 4] = g4;
        sarea[tid] = (g2 - g0) * (g3 - g1);   // fp32, as in reference _iou
    }
    __syncthreads();

    const int gidx = blockIdx.x * 256 + tid;
    const int a    = gidx >> 2;      // anchor index
    const int sub  = tid & 3;        // GT partition 0..3
    if (a >= N_TOTAL) return;

    // ---- Anchor reconstruction ----
    int rel, lvl;
    const float* loc;
    if (a < N_A3)      { lvl = 0; loc = loc3; rel = a; }
    else if (a < N_A4) { lvl = 1; loc = loc4; rel = a - N_A3; }
    else               { lvl = 2; loc = loc5; rel = a - N_A4; }
    const int li = rel / 3;
    const int ar = rel - li * 3;     // 0 -> 0.5, 1 -> 1.0, 2 -> 2.0

    const float2 xy = ((const float2*)loc)[li];
    // exact power-of-2 level scaling commutes with fp rounding
    const float scale = (float)(1 << lvl);
    const float hw = (ar == 0 ? hw_a : (ar == 1 ? 16.0f : hw_c)) * scale;
    const float hh = (ar == 0 ? hh_a : (ar == 1 ? 16.0f : hh_c)) * scale;

    const float x1 = xy.x - hw, y1 = xy.y - hh;
    const float x2 = xy.x + hw, y2 = xy.y + hh;
    const float wa = x2 - x1, ha = y2 - y1;
    const float xa = x1 + wa * 0.5f, ya = y1 + ha * 0.5f;
    const float a1 = wa * ha;

    // ---- partitioned IoU argmax (division-free) ----
    int   bj;
    float bi, bu;
    {
        const int j0 = sub * 16;
        {
            const float ltx = fmaxf(x1, sgt[j0 * 5 + 0]);
            const float lty = fmaxf(y1, sgt[j0 * 5 + 1]);
            const float rbx = fminf(x2, sgt[j0 * 5 + 2]);
            const float rby = fminf(y2, sgt[j0 * 5 + 3]);
            const float iw = fmaxf(rbx - ltx, 0.0f);
            const float ih = fmaxf(rby - lty, 0.0f);
            bi = iw * ih;
            bu = a1 + sarea[j0] - bi;
            bj = j0;
        }
        #pragma unroll
        for (int k = 1; k < 16; ++k) {
            const int j = j0 + k;
            const float ltx = fmaxf(x1, sgt[j * 5 + 0]);
            const float lty = fmaxf(y1, sgt[j * 5 + 1]);
            const float rbx = fminf(x2, sgt[j * 5 + 2]);
            const float rby = fminf(y2, sgt[j * 5 + 3]);
            const float iw = fmaxf(rbx - ltx, 0.0f);
            const float ih = fmaxf(rby - lty, 0.0f);
            const float inter = iw * ih;
            const float uni = a1 + sarea[j] - inter;
            // inter/uni > bi/bu  <=>  inter*bu > bi*uni   (uni, bu > 0)
            if (inter * bu > bi * uni) { bi = inter; bu = uni; bj = j; }
        }
    }
    // reduce across the 4 sub-lanes of this anchor (quads never straddle a wave)
    #pragma unroll
    for (int s = 1; s < 4; s <<= 1) {
        const float oi = __shfl_xor(bi, s, 64);
        const float ou = __shfl_xor(bu, s, 64);
        const int   oj = __shfl_xor(bj, s, 64);
        const float p_o = oi * bu, p_b = bi * ou;
        // strictly better, or equal quality with lower index (first-argmax)
        if (p_o > p_b || (p_o == p_b && oj < bj)) { bi = oi; bu = ou; bj = oj; }
    }

    const float q = bi / bu;   // single division, matches ref rounding

    // ---- sentinel ladder ----
    float m0, m1, m2, m3, m4;
    if (q <= 0.3f) {
        m0 = m1 = m2 = m3 = m4 = -1.0f;
    } else if (q < 0.6f) {
        m0 = m1 = m2 = m3 = m4 = SENTINEL;
    } else {
        const int off = bj * 5;
        m0 = sgt[off + 0]; m1 = sgt[off + 1]; m2 = sgt[off + 2];
        m3 = sgt[off + 3]; m4 = sgt[off + 4];
    }

    // ---- _apply_deltas -> proposals (stored by sub 0) ----
    const float4 d = ((const float4*)deltas)[a];
    const float dw = fminf(d.z, SCALE_CLAMP_F);
    const float dh = fminf(d.w, SCALE_CLAMP_F);
    const float xp = d.x * wa + xa;
    const float yp = d.y * ha + ya;
    const float wp = expf(dw) * wa;
    const float hp = expf(dh) * ha;
    float4 prop;
    prop.x = xp - wp * 0.5f;
    prop.y = yp - hp * 0.5f;
    prop.z = xp + wp * 0.5f;
    prop.w = yp + hp * 0.5f;

    // ---- _get_deltas (stored by sub 2) ----
    float o0, o1, o2, o3;
    if (m0 < 0.0f) {
        o0 = o1 = o2 = o3 = SENTINEL;
    } else {
        const float wg = fmaxf(m2 - m0, 1.0f);
        const float hg = fmaxf(m3 - m1, 1.0f);
        const float xg = m0 + wg * 0.5f;
        const float yg = m1 + hg * 0.5f;
        o0 = (xg - xa) / wa;
        o1 = (yg - ya) / ha;
        o2 = logf(wg / wa);
        o3 = logf(hg / ha);
    }

    if (sub == 0) {
        ((float4*)out)[a] = prop;                       // [0 .. 4N)
    } else if (sub == 1) {
        float* mout = out + N_TOTAL * 4 + a * 5;        // [4N .. 9N)
        mout[0] = m0; mout[1] = m1; mout[2] = m2; mout[3] = m3; mout[4] = m4;
    } else if (sub == 2) {
        float* g = out + N_TOTAL * 9 + a * 4;           // [9N .. 13N), 8B-aligned
        ((float2*)g)[0] = make_float2(o0, o1);
        ((float2*)g)[1] = make_float2(o2, o3);
    }
}

extern "C" void kernel_launch(void* const* d_in, const int* in_sizes, int n_in,
                              void* d_out, int out_size, void* d_ws, size_t ws_size,
                              hipStream_t stream) {
    const float* loc3   = (const float*)d_in[0];
    const float* loc4   = (const float*)d_in[1];
    const float* loc5   = (const float*)d_in[2];
    const float* deltas = (const float*)d_in[3];
    const float* gt     = (const float*)d_in[4];
    float* out = (float*)d_out;

    // Host-side double math mirrors Python: area=(4*8)^2=1024 at p3.
    // w = sqrt(area/ar); h = area/w; anchors use w/2, h/2 cast to fp32.
    const double w05 = sqrt(1024.0 / 0.5), h05 = 1024.0 / w05;   // ar = 0.5
    const double w20 = sqrt(1024.0 / 2.0), h20 = 1024.0 / w20;   // ar = 2.0
    const float hw_a = (float)(w05 * 0.5), hh_a = (float)(h05 * 0.5);
    const float hw_c = (float)(w20 * 0.5), hh_c = (float)(h20 * 0.5);

    const int block = 256;
    const int grid = (N_TOTAL * 4 + block - 1) / block;   // 593 blocks
    rpn_fused_v2<<<grid, block, 0, stream>>>(loc3, loc4, loc5, deltas, gt, out,
                                             hw_a, hh_a, hw_c, hh_c);
}